// Round 10
// baseline (6995.650 us; speedup 1.0000x reference)
//
#include <hip/hip_runtime.h>
#include <hip/hip_bf16.h>
#include <hip/hip_cooperative_groups.h>

namespace cg = cooperative_groups;

namespace {
constexpr int BATCH = 256;
constexpr int TENC  = 64;
constexpr int HID   = 1024;
constexpr int VOC   = 128;
constexpr int LDEC  = 32;
constexpr int G4    = 4 * HID;  // 4096
}

using ushortt = unsigned short;
using short8 = __attribute__((ext_vector_type(8))) short;   // 8 bf16 (4 VGPR)
using f32x4  = __attribute__((ext_vector_type(4))) float;   // MFMA acc

// async global->LDS DMA, 16B per lane (dest = wave-uniform base + lane*16).
__device__ __forceinline__ void async16(const void* g, void* l) {
  __builtin_amdgcn_global_load_lds(
      (const __attribute__((address_space(1))) void*)g,
      (__attribute__((address_space(3))) void*)l, 16, 0, 0);
}

// bf16 round-to-nearest-even split helpers
__device__ __forceinline__ ushortt f2bf(float x) {
  unsigned int u = __float_as_uint(x);
  return (ushortt)((u + 0x7fffu + ((u >> 16) & 1u)) >> 16);
}
__device__ __forceinline__ float bf2f(ushortt h) {
  return __uint_as_float(((unsigned int)h) << 16);
}

// ---------------------------------------------------------------------------
// init: zero h0, c, hpk0; tok = delimiter
// ---------------------------------------------------------------------------
__global__ __launch_bounds__(256) void k_init(float* __restrict__ h0,
                                              float* __restrict__ c,
                                              unsigned int* __restrict__ hpk0,
                                              int* __restrict__ tok) {
  int i = blockIdx.x * 256 + threadIdx.x;  // 0 .. 256*1024-1
  h0[i] = 0.f;
  c[i]  = 0.f;
  hpk0[i] = 0u;  // 2 splits * 256K ushort = 256K dwords
  if (i < BATCH) tok[i] = VOC - 1;
}

// ---------------------------------------------------------------------------
// Split U into bf16 hi/lo, MFMA-B-fragment-packed, OUTPUT-MAJOR (r8 layout,
// unchanged): chunk gid -> lanep=gid&63 (kq=lanep>>4,coln=lanep&15),
// u=gid>>6: f=u&7; v2=u>>3: ks=v2&31, ct=v2>>5; k=ks*32+kq*8+kk;
// n=(f>>1)*1024+ct*32+(f&1)*16+coln.
// ---------------------------------------------------------------------------
__global__ __launch_bounds__(256) void k_split_u(
    const float* __restrict__ enc_U, const float* __restrict__ dec_U,
    ushortt* __restrict__ enc_hi, ushortt* __restrict__ enc_lo,
    ushortt* __restrict__ dec_hi, ushortt* __restrict__ dec_lo) {
  const float* U;
  ushortt *hi_p, *lo_p;
  if (blockIdx.y == 0) { U = enc_U; hi_p = enc_hi; lo_p = enc_lo; }
  else                 { U = dec_U; hi_p = dec_hi; lo_p = dec_lo; }
  const int gid = blockIdx.x * 256 + threadIdx.x;  // chunk index
  const int lanep = gid & 63;
  const int kq = lanep >> 4, coln = lanep & 15;
  const int u = gid >> 6;
  const int f = u & 7;
  const int v2 = u >> 3;
  const int ks = v2 & 31, ct = v2 >> 5;
  const int n = (f >> 1) * HID + ct * 32 + (f & 1) * 16 + coln;
  const int kbase = ks * 32 + kq * 8;

  ushortt hv[8], lv[8];
#pragma unroll
  for (int kk = 0; kk < 8; ++kk) {
    const float x = U[(size_t)(kbase + kk) * G4 + n];
    hv[kk] = f2bf(x);
    lv[kk] = f2bf(x - bf2f(hv[kk]));
  }
  *(short8*)(hi_p + (size_t)gid * 8) = *(short8*)hv;
  *(short8*)(lo_p + (size_t)gid * 8) = *(short8*)lv;
}

// ---------------------------------------------------------------------------
// Precompute P[v][col] = emb[v] @ W[:,col] + b[col]. r8 structure + A_s
// both-sides XOR swizzle (rule #21): slot [row][q] holds k-quad
// q ^ ((row&7)<<2); source addr pre-swizzled, read applies same XOR.
// Kills the 4.2M same-column bank conflicts (32-way -> 8-way).
// ---------------------------------------------------------------------------
__global__ __launch_bounds__(256) void k_precompute(
    const float* __restrict__ enc_emb, const float* __restrict__ enc_W,
    const float* __restrict__ enc_b,   const float* __restrict__ dec_emb,
    const float* __restrict__ dec_W,   const float* __restrict__ dec_b,
    float* __restrict__ P_enc, float* __restrict__ P_dec) {
  const float* emb; const float* W; const float* bias; float* P;
  if (blockIdx.z == 0) { emb = enc_emb; W = enc_W; bias = enc_b; P = P_enc; }
  else                 { emb = dec_emb; W = dec_W; bias = dec_b; P = P_dec; }

  __shared__ float A_s[2][64][32];
  __shared__ float B_s[2][32][64];

  const int t    = threadIdx.x;
  const int col0 = blockIdx.x * 64;
  const int v0   = blockIdx.y * 64;
  const int tx   = t & 15;
  const int ty   = t >> 4;
  const int a_row = t >> 3, a_kq = (t & 7) * 4;
  const int a_kqs = a_kq ^ ((a_row & 7) << 2);  // pre-swizzled source quad
  const int b_k   = t >> 4, b_cq = (t & 15) * 4;

  float acc[4][4];
#pragma unroll
  for (int r = 0; r < 4; ++r)
#pragma unroll
    for (int j = 0; j < 4; ++j) acc[r][j] = 0.f;

  async16(&emb[(v0 + a_row) * HID + a_kqs], &A_s[0][a_row][a_kq]);
  async16(&emb[(v0 + 32 + a_row) * HID + a_kqs], &A_s[0][32 + a_row][a_kq]);
  async16(&W[b_k * G4 + col0 + b_cq], &B_s[0][b_k][b_cq]);
  async16(&W[(16 + b_k) * G4 + col0 + b_cq], &B_s[0][16 + b_k][b_cq]);

  for (int tile = 0; tile < 32; ++tile) {
    const int buf = tile & 1;
    __syncthreads();
    if (tile < 31) {
      const int nb = buf ^ 1;
      const int k0 = (tile + 1) * 32;
      async16(&emb[(v0 + a_row) * HID + k0 + a_kqs], &A_s[nb][a_row][a_kq]);
      async16(&emb[(v0 + 32 + a_row) * HID + k0 + a_kqs],
              &A_s[nb][32 + a_row][a_kq]);
      async16(&W[(k0 + b_k) * G4 + col0 + b_cq], &B_s[nb][b_k][b_cq]);
      async16(&W[(k0 + 16 + b_k) * G4 + col0 + b_cq],
              &B_s[nb][16 + b_k][b_cq]);
    }
#pragma unroll
    for (int k4 = 0; k4 < 32; k4 += 4) {
      float4 av[4];
#pragma unroll
      for (int r = 0; r < 4; ++r) {
        const int rr = ty * 4 + r;
        av[r] = *(const float4*)&A_s[buf][rr][k4 ^ ((rr & 7) << 2)];
      }
#pragma unroll
      for (int q = 0; q < 4; ++q) {
        const float4 b = *(const float4*)&B_s[buf][k4 + q][tx * 4];
#pragma unroll
        for (int r = 0; r < 4; ++r) {
          const float a = ((const float*)&av[r])[q];
          acc[r][0] += a * b.x;
          acc[r][1] += a * b.y;
          acc[r][2] += a * b.z;
          acc[r][3] += a * b.w;
        }
      }
    }
  }

  const float4 b4 = *(const float4*)&bias[col0 + tx * 4];
#pragma unroll
  for (int r = 0; r < 4; ++r) {
    float4 o;
    o.x = acc[r][0] + b4.x;
    o.y = acc[r][1] + b4.y;
    o.z = acc[r][2] + b4.z;
    o.w = acc[r][3] + b4.w;
    *(float4*)&P[(v0 + ty * 4 + r) * G4 + col0 + tx * 4] = o;
  }
}

// ---------------------------------------------------------------------------
// Fused persistent sequence kernel (cooperative): 64 enc + 32 dec steps.
// Per step: r8's barrier-free MFMA cell (12 MFMA/tile, lo*lo dropped) ->
// grid.sync -> [decoder: logits/softmax/argmax phase, 1 row per block ->
// grid.sync]. Block->XCD mapping is fixed for the whole kernel, so each
// XCD's 2MB U-split slice stays L2-resident across all steps.
// grid: 256 blocks (bx&31=ct, bx>>5=rt; ct%8 = XCD), 256 threads.
// ---------------------------------------------------------------------------
__global__ __launch_bounds__(256, 1) void k_seq(
    const int* __restrict__ inputs,
    const ushortt* __restrict__ enc_hi, const ushortt* __restrict__ enc_lo,
    const ushortt* __restrict__ dec_hi, const ushortt* __restrict__ dec_lo,
    const float* __restrict__ P_enc, const float* __restrict__ P_dec,
    const float* __restrict__ out_W, const float* __restrict__ out_b,
    float* __restrict__ h0b, float* __restrict__ h1b, float* __restrict__ c,
    ushortt* __restrict__ hpk0, ushortt* __restrict__ hpk1,
    int* __restrict__ tok, float* __restrict__ out) {
  cg::grid_group grid = cg::this_grid();
  const int bx = blockIdx.x;
  const int ct = bx & 31;
  const int rt = bx >> 5;
  const int j0 = ct * 32;
  const int r0 = rt * 32;
  const int t    = threadIdx.x;
  const int lane = t & 63;
  const int g    = t >> 6;  // wave id = gate

  __shared__ float z_s[32][132];   // cell gate-exchange
  __shared__ float h_row[HID];     // logits: one h row
  __shared__ float part[VOC];      // logits: upper-k partial
  __shared__ float red_v[VOC];
  __shared__ int   red_i[VOC];

  constexpr int ASTR = 16 * 64 * 8;  // hpk shorts per k-tile
  constexpr int BSTR = 8 * 64 * 8;   // U-split shorts per k-tile

#pragma unroll 1
  for (int step = 0; step < TENC + LDEC; ++step) {
    const bool enc = step < TENC;
    const ushortt* Uhi = enc ? enc_hi : dec_hi;
    const ushortt* Ulo = enc ? enc_lo : dec_lo;
    const float*   Pp  = enc ? P_enc : P_dec;
    const int par = step & 1;
    const ushortt* pin  = par ? hpk1 : hpk0;
    ushortt*       pout = par ? hpk0 : hpk1;
    const float*   hin  = par ? h1b : h0b;
    float*         hout = par ? h0b : h1b;
    const int* tidx = enc ? (inputs + step) : tok;
    const int  tstr = enc ? TENC : 1;

    // ---- cell phase: z = hin @ U via bf16 hi/lo MFMA --------------------
    const ushortt* pa[2][2];  // [m][split]
    const ushortt* pb[2][2];  // [nf][split]
#pragma unroll
    for (int m = 0; m < 2; ++m)
#pragma unroll
      for (int s = 0; s < 2; ++s)
        pa[m][s] =
            pin + ((((s * 32) * 16 + (rt * 2 + m)) * 64 + lane) << 3);
#pragma unroll
    for (int nf = 0; nf < 2; ++nf) {
      pb[nf][0] = Uhi + (((ct * 256 + (g * 2 + nf)) * 64 + lane) << 3);
      pb[nf][1] = Ulo + (((ct * 256 + (g * 2 + nf)) * 64 + lane) << 3);
    }

    short8 a[4][2][2], b[4][2][2];  // [phase][m|nf][split]
    f32x4 acc[2][2];
#pragma unroll
    for (int m = 0; m < 2; ++m)
#pragma unroll
      for (int n = 0; n < 2; ++n) acc[m][n] = (f32x4){0.f, 0.f, 0.f, 0.f};

#define LOADT(T, p)                                                          \
  {                                                                          \
    _Pragma("unroll") for (int m = 0; m < 2; ++m)                            \
        _Pragma("unroll") for (int s = 0; s < 2; ++s)                        \
            a[p][m][s] = *(const short8*)(pa[m][s] + (T) * ASTR);            \
    _Pragma("unroll") for (int nf = 0; nf < 2; ++nf)                         \
        _Pragma("unroll") for (int s = 0; s < 2; ++s)                        \
            b[p][nf][s] = *(const short8*)(pb[nf][s] + (T) * BSTR);          \
  }
#define MFMAT(p)                                                             \
  _Pragma("unroll") for (int m = 0; m < 2; ++m)                              \
      _Pragma("unroll") for (int n = 0; n < 2; ++n) {                        \
    acc[m][n] = __builtin_amdgcn_mfma_f32_16x16x32_bf16(                     \
        a[p][m][0], b[p][n][0], acc[m][n], 0, 0, 0);                         \
    acc[m][n] = __builtin_amdgcn_mfma_f32_16x16x32_bf16(                     \
        a[p][m][0], b[p][n][1], acc[m][n], 0, 0, 0);                         \
    acc[m][n] = __builtin_amdgcn_mfma_f32_16x16x32_bf16(                     \
        a[p][m][1], b[p][n][0], acc[m][n], 0, 0, 0);                         \
  }

    LOADT(0, 0)
    LOADT(1, 1)
    LOADT(2, 2)
    LOADT(3, 3)

    for (int T = 0; T < 32; T += 4) {
      MFMAT(0)
      if (T + 4 < 32) LOADT(T + 4, 0)
      MFMAT(1)
      if (T + 5 < 32) LOADT(T + 5, 1)
      MFMAT(2)
      if (T + 6 < 32) LOADT(T + 6, 2)
      MFMAT(3)
      if (T + 7 < 32) LOADT(T + 7, 3)
    }
#undef LOADT
#undef MFMAT

    // gate exchange: D frag (m,n): row=m*16+(lane>>4)*4+r, col=n*16+(lane&15)
#pragma unroll
    for (int m = 0; m < 2; ++m)
#pragma unroll
      for (int n = 0; n < 2; ++n)
#pragma unroll
        for (int r = 0; r < 4; ++r) {
          const int row = m * 16 + (lane >> 4) * 4 + r;
          const int col = n * 16 + (lane & 15);
          z_s[row][g * 32 + col] = acc[m][n][r];
        }
    __syncthreads();

    // epilogue: thread -> 4 (row, hidcol); gates, mask, write h/c/splits
    const int hc = t & 31;
#pragma unroll
    for (int p = 0; p < 4; ++p) {
      const int row  = (t >> 5) * 4 + p;
      const int grow = r0 + row;
      const int token = tidx[grow * tstr];
      const float* Px = Pp + (size_t)token * G4;
      const int col = j0 + hc;
      const float zi = z_s[row][hc]      + Px[col];
      const float zf = z_s[row][32 + hc] + Px[HID + col];
      const float zg = z_s[row][64 + hc] + Px[2 * HID + col];
      const float zo = z_s[row][96 + hc] + Px[3 * HID + col];
      const float ig = 1.f / (1.f + expf(-zi));
      const float fg = 1.f / (1.f + expf(-zf));
      const float gg = tanhf(zg);
      const float og = 1.f / (1.f + expf(-zo));
      const float c_old = c[grow * HID + col];
      const float c2 = fg * c_old + ig * gg;
      const float h2 = og * tanhf(c2);
      float hfin;
      if (token != 0) {
        hfin = h2;
        hout[grow * HID + col] = h2;
        c[grow * HID + col]    = c2;
      } else {
        hfin = hin[grow * HID + col];
        hout[grow * HID + col] = hfin;
      }
      const ushortt hi = f2bf(hfin);
      const ushortt lo = f2bf(hfin - bf2f(hi));
      const int kq = hc >> 3, kk = hc & 7;
      const int base =
          ((((ct)*16 + (grow >> 4)) * 64 + kq * 16 + (grow & 15)) << 3) + kk;
      pout[base] = hi;
      pout[(32 * 16 * 64 << 3) + base] = lo;
    }
    __syncthreads();
    grid.sync();  // h/c/hpk/(tok) visible grid-wide

    // ---- decoder: logits/softmax/argmax, 1 batch row per block ----------
    if (!enc) {
      const int drow = bx;
      *(float4*)&h_row[t * 4] = *(const float4*)&hout[drow * HID + t * 4];
      __syncthreads();
      const int v = t & 127, kh = t >> 7;
      float accl = (kh == 0) ? out_b[v] : 0.f;
      const float* wp = out_W + (size_t)(kh * 512) * VOC + v;
      const float* hp = h_row + kh * 512;
#pragma unroll 8
      for (int k = 0; k < 512; ++k) accl += hp[k] * wp[(size_t)k * VOC];
      if (kh) part[v] = accl;
      __syncthreads();
      const float full = accl + ((kh == 0) ? part[v] : 0.f);
      if (kh == 0) { red_v[v] = full; red_i[v] = v; }
      __syncthreads();
      for (int s = 64; s > 0; s >>= 1) {
        if (t < s) {
          const float ov = red_v[t + s];
          const int   oi = red_i[t + s];
          if (ov > red_v[t] || (ov == red_v[t] && oi < red_i[t])) {
            red_v[t] = ov;
            red_i[t] = oi;
          }
        }
        __syncthreads();
      }
      const float mx = red_v[0];
      const int amax = red_i[0];
      __syncthreads();
      float e = 0.f;
      if (kh == 0) {
        e = expf(full - mx);
        red_v[v] = e;
      }
      __syncthreads();
      for (int s = 64; s > 0; s >>= 1) {
        if (t < s) red_v[t] += red_v[t + s];
        __syncthreads();
      }
      const int ds = step - TENC;
      if (kh == 0)
        out[(size_t)drow * (LDEC * VOC) + ds * VOC + v] = e / red_v[0];
      if (t == 0) {
        tok[drow] = amax;
        out[(size_t)BATCH * LDEC * VOC + ds * BATCH + drow] = (float)amax;
      }
      __syncthreads();
      grid.sync();  // tok visible before next cell phase
    }
  }
}

// ---------------------------------------------------------------------------
extern "C" void kernel_launch(void* const* d_in, const int* in_sizes, int n_in,
                              void* d_out, int out_size, void* d_ws,
                              size_t ws_size, hipStream_t stream) {
  (void)in_sizes; (void)n_in; (void)out_size; (void)ws_size;
  const int*   inputs  = (const int*)d_in[0];
  const float* enc_emb = (const float*)d_in[2];
  const float* enc_W   = (const float*)d_in[3];
  const float* enc_U   = (const float*)d_in[4];
  const float* enc_b   = (const float*)d_in[5];
  const float* dec_emb = (const float*)d_in[6];
  const float* dec_W   = (const float*)d_in[7];
  const float* dec_U   = (const float*)d_in[8];
  const float* dec_b   = (const float*)d_in[9];
  const float* out_W   = (const float*)d_in[10];
  const float* out_b   = (const float*)d_in[11];
  float* out = (float*)d_out;

  float* ws    = (float*)d_ws;
  float* P_enc = ws;                        // 512K floats
  float* P_dec = P_enc + VOC * G4;          // 512K
  float* h0    = P_dec + VOC * G4;          // 256K
  float* h1    = h0 + BATCH * HID;          // 256K
  float* c     = h1 + BATCH * HID;          // 256K
  int*   tok   = (int*)(c + BATCH * HID);   // 256 (pad to 256 words)
  ushortt* enc_hi = (ushortt*)(tok + 256);  // 4.19M ushort each
  ushortt* enc_lo = enc_hi + (size_t)HID * G4;
  ushortt* dec_hi = enc_lo + (size_t)HID * G4;
  ushortt* dec_lo = dec_hi + (size_t)HID * G4;
  ushortt* hpk0   = dec_lo + (size_t)HID * G4;  // 512K ushort
  ushortt* hpk1   = hpk0 + 2 * BATCH * HID;     // 512K ushort

  k_init<<<(BATCH * HID) / 256, 256, 0, stream>>>(h0, c, (unsigned int*)hpk0,
                                                  tok);

  dim3 sgrid((HID * G4) / 8 / 256, 2);
  k_split_u<<<sgrid, 256, 0, stream>>>(enc_U, dec_U, enc_hi, enc_lo, dec_hi,
                                       dec_lo);

  dim3 pgrid(G4 / 64, 2, 2);
  k_precompute<<<pgrid, 256, 0, stream>>>(enc_emb, enc_W, enc_b, dec_emb,
                                          dec_W, dec_b, P_enc, P_dec);

  void* kargs[] = {(void*)&inputs, (void*)&enc_hi, (void*)&enc_lo,
                   (void*)&dec_hi, (void*)&dec_lo, (void*)&P_enc,
                   (void*)&P_dec,  (void*)&out_W,  (void*)&out_b,
                   (void*)&h0,     (void*)&h1,     (void*)&c,
                   (void*)&hpk0,   (void*)&hpk1,   (void*)&tok,
                   (void*)&out};
  hipLaunchCooperativeKernel((void*)k_seq, dim3(256), dim3(256), kargs, 0,
                             stream);
}